// Round 3
// baseline (514.704 us; speedup 1.0000x reference)
//
#include <hip/hip_runtime.h>
#include <math.h>

#define N 8192
#define NW 128          // 64-bit mask words per row
#define FIN 29
#define FH 8
#define NH 4
#define ALPHA 0.2f
#define LOG2E 1.4426950408889634f
#define JS 4            // layer-1 j-splits
#define JRR (N / JS)    // 2048

typedef unsigned long long ull;
typedef unsigned short u16;
typedef __attribute__((ext_vector_type(8))) short bf16x8;
typedef __attribute__((ext_vector_type(4))) float f32x4;
typedef __attribute__((ext_vector_type(2))) float f32x2;

__device__ inline unsigned bf16rn(float f) {
    unsigned u = __float_as_uint(f);
    return (u + 0x7fffu + ((u >> 16) & 1u)) >> 16;
}
// monotone float <-> unsigned encoding for atomicMax
__device__ inline unsigned fenc(float x) {
    unsigned u = __float_as_uint(x);
    return (u & 0x80000000u) ? ~u : (u | 0x80000000u);
}
__device__ inline float fdec(unsigned e) {
    return __uint_as_float((e & 0x80000000u) ? (e & 0x7fffffffu) : ~e);
}
// packed f32 pair multiply (VOP3P) — one instruction, two products
__device__ inline f32x2 pk_mul(f32x2 a, f32x2 b) {
    f32x2 d;
    asm("v_pk_mul_f32 %0, %1, %2" : "=v"(d) : "v"(a), "v"(b));
    return d;
}

// ---------------- K0: pack adj (256 MB int32) into row-major bitmask (8 MB) ----------------
// HBM-bound floor ~42 us. bit of word w=(i*4+wave), lane <-> element i*256+tid.
__global__ void k0_pack(const int* __restrict__ adj, ull* __restrict__ mask,
                        unsigned* __restrict__ amax) {
    int row = blockIdx.x;
    int tid = threadIdx.x;
    int lane = tid & 63;
    int wave = tid >> 6;
    if (row == 0 && tid < 8) amax[tid] = 0u;   // init atomic-max slots
    const int* rp = adj + (size_t)row * N;
#pragma unroll 8
    for (int i = 0; i < 32; i++) {
        int a = rp[i * 256 + tid];
        ull b = __ballot(a > 0);
        if (lane == 0) mask[(size_t)row * NW + i * 4 + wave] = b;
    }
}

// ---------------- K0t: word-level transpose mask -> maskT[word][row] ----------------
// Kills k3's 16-line mask gather: lanes then read 16 consecutive ull (128 B).
// 64x64-word LDS tiles, pad to 65 to keep b64 reads at free 2-way banking.
__global__ __launch_bounds__(256) void k0t_transpose(
    const ull* __restrict__ mask, ull* __restrict__ maskT) {
    __shared__ ull sT[64][65];   // 33.3 KB
    int tid = threadIdx.x;
    int ln = tid & 63;
    int wv = tid >> 6;
    int br = blockIdx.x >> 1;    // row tile 0..127
    int bw = blockIdx.x & 1;     // word tile 0..1
#pragma unroll
    for (int i = 0; i < 16; i++) {
        int rr = i * 4 + wv;
        sT[rr][ln] = mask[(size_t)(br * 64 + rr) * NW + bw * 64 + ln];
    }
    __syncthreads();
#pragma unroll
    for (int i = 0; i < 16; i++) {
        int ww = i * 4 + wv;
        maskT[(size_t)(bw * 64 + ww) * N + br * 64 + ln] = sT[ln][ww];
    }
}

// ---------------- K1: per-node features, one thread per (node, head) ----------------
// Outputs:
//   e2p/e2n[h][j] = exp2(f2L) / exp2(ALPHA*f2L)  -- split arrays so k3 can pk_mul
//   Bpk           = MFMA B operand pre-packed in fragment order (c=8 -> ones col)
//   f1a[j*4+h]    = f1L ; amax[h] = max_j f2L
__global__ __launch_bounds__(256) void k1_feat(
    const float* __restrict__ x, const float* __restrict__ Wh,
    const float* __restrict__ ah,
    float* __restrict__ e2p, float* __restrict__ e2n, u16* __restrict__ Bpk,
    float* __restrict__ f1a, unsigned* __restrict__ amax) {
    __shared__ float sx[64 * FIN];      // 7.4 KB
    __shared__ float sW[NH * FIN * FH];
    __shared__ float sa[NH * 2 * FH];
    int tid = threadIdx.x;
    for (int i = tid; i < NH * FIN * FH; i += 256) sW[i] = Wh[i];
    for (int i = tid; i < NH * 2 * FH; i += 256) sa[i] = ah[i];
    for (int i = tid; i < 64 * FIN; i += 256) sx[i] = x[(size_t)blockIdx.x * 64 * FIN + i];
    __syncthreads();
    int h = tid & 3;
    int nl = tid >> 2;                  // node-local 0..63
    int node = blockIdx.x * 64 + nl;
    float hv[FH];
#pragma unroll
    for (int k = 0; k < FH; k++) {
        float s = 0.f;
#pragma unroll
        for (int f = 0; f < FIN; f++) s += sx[nl * FIN + f] * sW[(h * FIN + f) * FH + k];
        hv[k] = s;
    }
    float f1 = 0.f, f2 = 0.f;
#pragma unroll
    for (int k = 0; k < FH; k++) {
        f1 += hv[k] * sa[h * 16 + k];
        f2 += hv[k] * sa[h * 16 + 8 + k];
    }
    float f1L = f1 * LOG2E, f2L = f2 * LOG2E;
    f1a[node * 4 + h] = f1L;
    e2p[(size_t)h * N + node] = __builtin_amdgcn_exp2f(f2L);
    e2n[(size_t)h * N + node] = __builtin_amdgcn_exp2f(ALPHA * f2L);
    // fragment-order pack
    int js = node >> 11;
    int t  = (node >> 6) & 31;
    int hfl = (node >> 5) & 1;
    int kb = (node >> 3) & 3;
    int e  = node & 7;
    u16* dst = Bpk + ((size_t)(((h * 4 + js) * 32 + t) * 2 + hfl)) * 512 + e;
#pragma unroll
    for (int cc = 0; cc < 16; cc++) {
        u16 v = (cc < FH) ? (u16)bf16rn(hv[cc])
                          : ((cc == 8) ? (u16)0x3F80u : (u16)0);
        dst[(kb * 16 + cc) * 8] = v;
    }
    // per-head global max of f2L (offs 4..32 keep head classes separate)
    float v = f2L;
    for (int off = 4; off < 64; off <<= 1) v = fmaxf(v, __shfl_xor(v, off, 64));
    if ((tid & 63) < 4) atomicMax(&amax[tid & 3], fenc(v));
}

// ---------------- K3: layer-1 attention via MFMA, maskT coalesced, pk_mul ----------------
// w_ij = exp2(lrelu(f1+f2) - m) = max(E1p_i*E2p_j, E1n_i*E2n_j)  (exp2 monotone)
// Block: 256 thr = 4 waves; each wave owns TWO 16-row tiles (r0, r0+64) sharing
// B fragment and e2 loads. All loads now coalesced: mask via maskT (128 B per
// 16-lane group), B via Bpk, e2 via 16B broadcast quads.
#define WTILE(E1P2, E1N2, SW, ACC)                                              \
    {                                                                           \
        f32x2 wp, wn;                                                           \
        float w0, w1, w2, w3, w4, w5, w6, w7;                                   \
        wp = pk_mul(E1P2, p01); wn = pk_mul(E1N2, n01);                         \
        w0 = fmaxf(wp[0], wn[0]); w1 = fmaxf(wp[1], wn[1]);                     \
        wp = pk_mul(E1P2, p23); wn = pk_mul(E1N2, n23);                         \
        w2 = fmaxf(wp[0], wn[0]); w3 = fmaxf(wp[1], wn[1]);                     \
        wp = pk_mul(E1P2, p45); wn = pk_mul(E1N2, n45);                         \
        w4 = fmaxf(wp[0], wn[0]); w5 = fmaxf(wp[1], wn[1]);                     \
        wp = pk_mul(E1P2, p67); wn = pk_mul(E1N2, n67);                         \
        w6 = fmaxf(wp[0], wn[0]); w7 = fmaxf(wp[1], wn[1]);                     \
        w0 = (SW & 1u)   ? w0 : 0.f;                                            \
        w1 = (SW & 2u)   ? w1 : 0.f;                                            \
        w2 = (SW & 4u)   ? w2 : 0.f;                                            \
        w3 = (SW & 8u)   ? w3 : 0.f;                                            \
        w4 = (SW & 16u)  ? w4 : 0.f;                                            \
        w5 = (SW & 32u)  ? w5 : 0.f;                                            \
        w6 = (SW & 64u)  ? w6 : 0.f;                                            \
        w7 = (SW & 128u) ? w7 : 0.f;                                            \
        uint4 ap;                                                               \
        asm("v_cvt_pk_bf16_f32 %0, %1, %2" : "=v"(ap.x) : "v"(w0), "v"(w1));    \
        asm("v_cvt_pk_bf16_f32 %0, %1, %2" : "=v"(ap.y) : "v"(w2), "v"(w3));    \
        asm("v_cvt_pk_bf16_f32 %0, %1, %2" : "=v"(ap.z) : "v"(w4), "v"(w5));    \
        asm("v_cvt_pk_bf16_f32 %0, %1, %2" : "=v"(ap.w) : "v"(w6), "v"(w7));    \
        ACC = __builtin_amdgcn_mfma_f32_16x16x32_bf16(                          \
            __builtin_bit_cast(bf16x8, ap), __builtin_bit_cast(bf16x8, bp),     \
            ACC, 0, 0, 0);                                                      \
    }

__global__ __launch_bounds__(256, 4) void k3_attn1(
    const ull* __restrict__ maskT, const float* __restrict__ e2p,
    const float* __restrict__ e2n, const uint4* __restrict__ Bpk,
    const float* __restrict__ f1a, const unsigned* __restrict__ amax,
    float* __restrict__ part1) {
    int tid = threadIdx.x;
    int lane = tid & 63;
    int wave = tid >> 6;
    int h = blockIdx.x & 3;
    int js = (blockIdx.x >> 2) & 3;
    int rowblk = blockIdx.x >> 4;        // 0..63
    int jbase = js * JRR;

    int c = lane & 15;                   // B col / A row selector
    int kb = lane >> 4;                  // k-group 0..3
    int sh = kb * 8;
    int r0 = rowblk * 128 + wave * 16 + c;
    int r1 = r0 + 64;

    float mfL = fdec(amax[h]);
    float f1 = f1a[r0 * 4 + h];
    float vv = f1 + mfL, mm = fmaxf(vv, ALPHA * vv);
    f32x2 e1p0 = {0.f, 0.f}, e1n0 = {0.f, 0.f}, e1p1 = {0.f, 0.f}, e1n1 = {0.f, 0.f};
    e1p0[0] = e1p0[1] = __builtin_amdgcn_exp2f(f1 - mm);
    e1n0[0] = e1n0[1] = __builtin_amdgcn_exp2f(ALPHA * f1 - mm);
    f1 = f1a[r1 * 4 + h];
    vv = f1 + mfL; mm = fmaxf(vv, ALPHA * vv);
    e1p1[0] = e1p1[1] = __builtin_amdgcn_exp2f(f1 - mm);
    e1n1[0] = e1n1[1] = __builtin_amdgcn_exp2f(ALPHA * f1 - mm);

    const ull* mT = maskT + (size_t)(jbase >> 6) * N;
    const float* pph = e2p + (size_t)h * N + jbase + kb * 8;
    const float* nnh = e2n + (size_t)h * N + jbase + kb * 8;
    const uint4* bp0 = Bpk + (size_t)(h * 4 + js) * 4096 + lane;

    f32x4 acc0 = {0.f, 0.f, 0.f, 0.f};
    f32x4 acc1 = {0.f, 0.f, 0.f, 0.f};

    for (int t = 0; t < JRR / 64; t++) {   // 32
        ull mw0 = mT[(size_t)t * N + r0];   // 128 B contiguous per 16-lane group
        ull mw1 = mT[(size_t)t * N + r1];
#pragma unroll
        for (int hf = 0; hf < 2; hf++) {
            f32x4 P0 = *(const f32x4*)(pph + t * 64 + hf * 32);
            f32x4 P1 = *(const f32x4*)(pph + t * 64 + hf * 32 + 4);
            f32x4 Q0 = *(const f32x4*)(nnh + t * 64 + hf * 32);
            f32x4 Q1 = *(const f32x4*)(nnh + t * 64 + hf * 32 + 4);
            f32x2 p01 = __builtin_shufflevector(P0, P0, 0, 1);
            f32x2 p23 = __builtin_shufflevector(P0, P0, 2, 3);
            f32x2 p45 = __builtin_shufflevector(P1, P1, 0, 1);
            f32x2 p67 = __builtin_shufflevector(P1, P1, 2, 3);
            f32x2 n01 = __builtin_shufflevector(Q0, Q0, 0, 1);
            f32x2 n23 = __builtin_shufflevector(Q0, Q0, 2, 3);
            f32x2 n45 = __builtin_shufflevector(Q1, Q1, 0, 1);
            f32x2 n67 = __builtin_shufflevector(Q1, Q1, 2, 3);
            uint4 bp = bp0[(t * 2 + hf) * 64];
            unsigned sw0 = ((unsigned)(mw0 >> (hf * 32))) >> sh;
            unsigned sw1 = ((unsigned)(mw1 >> (hf * 32))) >> sh;
            WTILE(e1p0, e1n0, sw0, acc0)
            WTILE(e1p1, e1n1, sw1, acc1)
        }
    }
    if (c <= 8) {   // cols 0..7 = features, 8 = denominator
        int ro = rowblk * 128 + wave * 16 + kb * 4;
        float* dst = part1 + (size_t)(js * 36 + h * 9 + c) * N + ro;
        *(float4*)dst = make_float4(acc0[0], acc0[1], acc0[2], acc0[3]);
        *(float4*)(dst + 64) = make_float4(acc1[0], acc1[1], acc1[2], acc1[3]);
    }
}

// ---------------- K3b: finalize layer 1 + layer-2 features + fused layer-2 max ----------------
__global__ void k3b_final(const float* __restrict__ part1, const float* __restrict__ Wo,
                          const float* __restrict__ ao,
                          float4* __restrict__ rec2, float* __restrict__ f1b,
                          unsigned* __restrict__ amax) {
    __shared__ float sW[64];
    __shared__ float sa[4];
    int tid = threadIdx.x;
    if (tid < 64) sW[tid] = Wo[tid];
    if (tid < 4) sa[tid] = ao[tid];
    __syncthreads();
    int row = blockIdx.x * 256 + tid;
    float hv[32];
#pragma unroll
    for (int h = 0; h < NH; h++) {
        float s[9];
#pragma unroll
        for (int cc = 0; cc < 9; cc++) {
            float acc = 0.f;
#pragma unroll
            for (int js = 0; js < JS; js++)
                acc += part1[(size_t)(js * 36 + h * 9 + cc) * N + row];
            s[cc] = acc;
        }
        float inv = 1.f / s[8];
#pragma unroll
        for (int k = 0; k < FH; k++) {
            float o = s[k] * inv;
            hv[h * 8 + k] = (o > 0.f) ? o : expm1f(o);
        }
    }
    float h0 = 0.f, h1 = 0.f;
#pragma unroll
    for (int i = 0; i < 32; i++) {
        h0 = fmaf(hv[i], sW[i * 2 + 0], h0);
        h1 = fmaf(hv[i], sW[i * 2 + 1], h1);
    }
    float f1 = (h0 * sa[0] + h1 * sa[1]) * LOG2E;
    float f2 = (h0 * sa[2] + h1 * sa[3]) * LOG2E;
    rec2[row] = make_float4(__builtin_amdgcn_exp2f(f2), h0, h1,
                            __builtin_amdgcn_exp2f(ALPHA * f2));
    f1b[row] = f1;
    float vmax = f2;
    for (int off = 32; off > 0; off >>= 1) vmax = fmaxf(vmax, __shfl_xor(vmax, off, 64));
    if ((tid & 63) == 0) atomicMax(&amax[4], fenc(vmax));
}

// ---------------- K6: layer-2 attention + finalize + log_softmax (fused) ----------------
// Each block owns 8 rows end-to-end (full column sweep) -> no partials, no k6b.
// maskT gives the wave's two row-words in one cache line per s.
__global__ __launch_bounds__(256) void k6_attn2(
    const ull* __restrict__ maskT, const float4* __restrict__ rec2,
    const float* __restrict__ f1b, const unsigned* __restrict__ amax,
    float* __restrict__ out) {
    int tid = threadIdx.x;
    int lane = tid & 63;
    int wave = tid >> 6;
    int r0 = blockIdx.x * 8 + wave * 2;   // rows r0, r0+1

    float mb = fdec(amax[4]);
    float f1 = f1b[r0];
    float v = f1 + mb, m = fmaxf(v, ALPHA * v);
    float e1p0 = __builtin_amdgcn_exp2f(f1 - m);
    float e1n0 = __builtin_amdgcn_exp2f(ALPHA * f1 - m);
    f1 = f1b[r0 + 1];
    v = f1 + mb; m = fmaxf(v, ALPHA * v);
    float e1p1 = __builtin_amdgcn_exp2f(f1 - m);
    float e1n1 = __builtin_amdgcn_exp2f(ALPHA * f1 - m);

    float a00 = 0.f, a10 = 0.f, d0 = 0.f;
    float a01 = 0.f, a11 = 0.f, d1 = 0.f;
#pragma unroll 4
    for (int s = 0; s < NW; s++) {   // 128
        float4 q = rec2[s * 64 + lane];
        ull mw0 = maskT[(size_t)s * N + r0];
        ull mw1 = maskT[(size_t)s * N + r0 + 1];
        float w0 = fmaxf(e1p0 * q.x, e1n0 * q.w);
        w0 = ((mw0 >> lane) & 1ull) ? w0 : 0.f;
        float w1 = fmaxf(e1p1 * q.x, e1n1 * q.w);
        w1 = ((mw1 >> lane) & 1ull) ? w1 : 0.f;
        a00 = fmaf(w0, q.y, a00);
        a10 = fmaf(w0, q.z, a10);
        d0 += w0;
        a01 = fmaf(w1, q.y, a01);
        a11 = fmaf(w1, q.z, a11);
        d1 += w1;
    }
    for (int off = 32; off > 0; off >>= 1) {
        a00 += __shfl_xor(a00, off, 64);
        a10 += __shfl_xor(a10, off, 64);
        d0  += __shfl_xor(d0,  off, 64);
        a01 += __shfl_xor(a01, off, 64);
        a11 += __shfl_xor(a11, off, 64);
        d1  += __shfl_xor(d1,  off, 64);
    }
    if (lane == 0) {
#pragma unroll
        for (int i = 0; i < 2; i++) {
            float s0 = i ? a01 : a00;
            float s1 = i ? a11 : a10;
            float dd = i ? d1 : d0;
            float inv = 1.f / dd;
            float e0 = s0 * inv, e1 = s1 * inv;
            e0 = (e0 > 0.f) ? e0 : expm1f(e0);
            e1 = (e1 > 0.f) ? e1 : expm1f(e1);
            float mx = fmaxf(e0, e1);
            float lse = mx + logf(expf(e0 - mx) + expf(e1 - mx));
            ((float2*)out)[r0 + i] = make_float2(e0 - lse, e1 - lse);
        }
    }
}

extern "C" void kernel_launch(void* const* d_in, const int* in_sizes, int n_in,
                              void* d_out, int out_size, void* d_ws, size_t ws_size,
                              hipStream_t stream) {
    const float* x   = (const float*)d_in[0];
    const int*   adj = (const int*)d_in[1];
    const float* Wh  = (const float*)d_in[2];
    const float* ah  = (const float*)d_in[3];
    const float* Wo  = (const float*)d_in[4];
    const float* ao  = (const float*)d_in[5];
    float* out = (float*)d_out;
    float* ws = (float*)d_ws;

    // workspace layout (float offsets)
    ull*      mask  = (ull*)ws;                       // 8 MB = 2097152 floats
    ull*      maskT = (ull*)(ws + 2097152);           // 8 MB word-transposed
    float*    e2p   = ws + 4194304;                   // 4*N
    float*    e2n   = ws + 4227072;                   // 4*N
    u16*      Bpk   = (u16*)(ws + 4259840);           // 1 MB = 262144 floats
    float*    f1a   = ws + 4521984;                   // 4*N
    float*    part1 = ws + 4554752;                   // 4*36*N = 1179648
    float4*   rec2  = (float4*)(ws + 5734400);        // N float4
    float*    f1b   = ws + 5767168;                   // N
    unsigned* amax  = (unsigned*)(ws + 5775360);      // 8 slots (0..3 heads, 4 layer2)

    k0_pack<<<N, 256, 0, stream>>>(adj, mask, amax);
    k0t_transpose<<<256, 256, 0, stream>>>(mask, maskT);
    k1_feat<<<N / 64, 256, 0, stream>>>(x, Wh, ah, e2p, e2n, Bpk, f1a, amax);
    k3_attn1<<<(N / 128) * JS * NH, 256, 0, stream>>>(maskT, e2p, e2n, (const uint4*)Bpk,
                                                      f1a, amax, part1);
    k3b_final<<<N / 256, 256, 0, stream>>>(part1, Wo, ao, rec2, f1b, amax);
    k6_attn2<<<N / 8, 256, 0, stream>>>(maskT, rec2, f1b, amax, out);
}